// Round 4
// baseline (1624.974 us; speedup 1.0000x reference)
//
#include <hip/hip_runtime.h>
#include <hip/hip_bf16.h>

// Problem constants (from reference)
#define N_ENC 500000
#define N_PAT 100000
#define D 64
#define HID 128
#define NE 1000000

typedef unsigned short ushort_t;
typedef unsigned int uint_t;
typedef __attribute__((ext_vector_type(8))) short bfrag8;   // 8 x bf16 (4 VGPRs)
typedef __attribute__((ext_vector_type(4))) float f32x4;

// Bucketing: pe direction (dst=encounters) 256 dsts/bucket; ep (dst=patients) 128.
#define BS_PE 256
#define SH_PE 8
#define NB_PE 1954        // ceil(500000/256)
#define BS_EP 128
#define SH_EP 7
#define NB_EP 782         // ceil(100000/128)

// Workspace layout (float units). Zeroed region first (one small memset).
#define OFF_SUM2    0               // 500,000
#define OFF_HIST_PE 500000          // 2048 ints
#define OFF_HIST_EP 502048          // 2048 ints
#define ZERO_FLOATS 504096          // ~2.0 MB zeroed
#define OFF_AGG_ENC 504096          // 500,000*64 bf16 = 16,000,000 floats
#define OFF_AGG_PAT 16504096        // 100,000*64 bf16 = 3,200,000 floats
#define OFF_CNT_ENC 19704096        // 500,000
#define OFF_CNT_PAT 20204096        // 100,000
#define OFF_SPAT    20304096        // 100,000
#define OFF_FRAGS   20404096        // 4 matrices * 8192 ushort = 16,384 floats
#define OFF_WL2C    20420480        // 128
#define OFF_WR2C    20420608        // 128
#define OFF_C0      20420736        // 64 (padded)
#define OFF_BASE_PE 20420800        // 2048 ints
#define OFF_CUR_PE  20422848        // 2048 ints
#define OFF_BASE_EP 20424896        // 2048 ints
#define OFF_CUR_EP  20426944       // 2048 ints
#define OFF_RECS_PE 20428992        // 1M int2 = 2,000,000 floats (8B-aligned: even)
#define OFF_RECS_EP 22428992        // 1M int2
// end ~24.4M floats ~98 MB

__device__ inline ushort_t f2bf(float x) {
    // round-to-nearest-even f32 -> bf16
    uint_t u = __float_as_uint(x);
    u += 0x7fffu + ((u >> 16) & 1u);
    return (ushort_t)(u >> 16);
}

// ---------------- Prep (unchanged logic) ----------------
__global__ __launch_bounds__(256) void prep_kernel(
    const float* __restrict__ Wl_pe1, const float* __restrict__ Wr_pe1,
    const float* __restrict__ Wl_ep1, const float* __restrict__ Wr_ep1,
    const float* __restrict__ Wl_pe2, const float* __restrict__ Wr_pe2,
    const float* __restrict__ b_pe2, const float* __restrict__ Wc,
    const float* __restrict__ bc, float* __restrict__ ws)
{
    int t = blockIdx.x * blockDim.x + threadIdx.x;
    const int total = 4 * 8192;
    ushort_t* fr = (ushort_t*)(ws + OFF_FRAGS);
    for (int i = t; i < total; i += gridDim.x * blockDim.x) {
        int mtx = i >> 13;
        int r = i & 8191;
        int jj = r & 7;
        int l = (r >> 3) & 63;
        int ft = r >> 9;          // 0..15 = jt*2+kt
        int kt = ft & 1;
        int jt = ft >> 1;
        int k = kt * 32 + (l >> 4) * 8 + jj;
        int j = jt * 16 + (l & 15);
        const float* W = (mtx == 0) ? Wl_pe1 : (mtx == 1) ? Wr_pe1
                       : (mtx == 2) ? Wl_ep1 : Wr_ep1;
        fr[i] = f2bf(W[k * HID + j]);
    }
    if (blockIdx.x == 0) {
        int tid = threadIdx.x;
        if (tid < HID) {
            float s1 = 0.f, s2 = 0.f;
            for (int j = 0; j < HID; j++) {
                float wc = Wc[j];
                s1 += Wl_pe2[tid * HID + j] * wc;
                s2 += Wr_pe2[tid * HID + j] * wc;
            }
            ws[OFF_WL2C + tid] = s1;
            ws[OFF_WR2C + tid] = s2;
            if (tid == 0) {
                float c0 = bc[0];
                for (int j = 0; j < HID; j++) c0 += b_pe2[j] * Wc[j];
                ws[OFF_C0] = c0;
            }
        }
    }
}

// ---------------- Bucketed aggregation (counting sort + LDS accumulate) -----

// Histogram of dst >> shift into hist[2048] (pre-zeroed).
__global__ __launch_bounds__(256) void hist_kernel(
    const int* __restrict__ dst, int E, int* __restrict__ hist, int shift)
{
    __shared__ int h[2048];
    for (int i = threadIdx.x; i < 2048; i += 256) h[i] = 0;
    __syncthreads();
    for (int e = blockIdx.x * 256 + threadIdx.x; e < E; e += gridDim.x * 256)
        atomicAdd(&h[dst[e] >> shift], 1);
    __syncthreads();
    for (int i = threadIdx.x; i < 2048; i += 256)
        if (h[i]) atomicAdd(&hist[i], h[i]);
}

// Exclusive scan of hist[0..2047] -> base, cursor. Single block, 1024 threads.
__global__ __launch_bounds__(1024) void scan_kernel(
    const int* __restrict__ hist, int* __restrict__ base, int* __restrict__ cursor)
{
    __shared__ int buf[1024];
    int t = threadIdx.x;
    int a = hist[2 * t], b = hist[2 * t + 1];
    int s = a + b;
    buf[t] = s;
    __syncthreads();
    for (int off = 1; off < 1024; off <<= 1) {
        int v = (t >= off) ? buf[t - off] : 0;
        __syncthreads();
        buf[t] += v;
        __syncthreads();
    }
    int ex = buf[t] - s;   // exclusive prefix over pairs
    base[2 * t] = ex;      base[2 * t + 1] = ex + a;
    cursor[2 * t] = ex;    cursor[2 * t + 1] = ex + a;
}

// Place edges into bucket-contiguous records (src, dstLocal).
__global__ __launch_bounds__(256) void place_kernel(
    const int* __restrict__ src, const int* __restrict__ dst, int E,
    int* __restrict__ cursor, int2* __restrict__ recs, int shift, int mask)
{
    int e = blockIdx.x * 256 + threadIdx.x;
    if (e >= E) return;
    int d = dst[e];
    int pos = atomicAdd(&cursor[d >> shift], 1);
    recs[pos] = make_int2(src[e], d & mask);
}

// One block per bucket: gather source rows (wave-per-edge, coalesced 256B),
// accumulate into LDS f32 via LDS atomics, write agg (bf16) + cnt once.
template <int BS>
__global__ __launch_bounds__(256) void agg_kernel(
    const float* __restrict__ xsrc, const int2* __restrict__ recs,
    const int* __restrict__ base, ushort_t* __restrict__ agg,
    float* __restrict__ cnt, int n_dst)
{
    __shared__ float acc[BS * 64];
    __shared__ float cl[BS];
    int tid = threadIdx.x;
    {
        float4* a4 = (float4*)acc;
        for (int i = tid; i < BS * 16; i += 256) a4[i] = make_float4(0.f, 0.f, 0.f, 0.f);
        if (tid < BS) cl[tid] = 0.f;
    }
    __syncthreads();
    int b = blockIdx.x;
    int s0 = base[b], s1 = base[b + 1];
    int lane = tid & 63, w = tid >> 6;
    for (int i = s0 + w * 64; i < s1; i += 256) {
        int j = i + lane;
        int2 r = (j < s1) ? recs[j] : make_int2(0, 0);
        int m = s1 - i;
        if (m >= 64) {
#pragma unroll 8
            for (int k = 0; k < 64; k++) {
                int sidx = __shfl(r.x, k);
                int dl = __shfl(r.y, k);
                float v = xsrc[(size_t)sidx * 64 + lane];
                atomicAdd(&acc[dl * 64 + lane], v);
                if (lane == 0) atomicAdd(&cl[dl], 1.f);
            }
        } else {
            for (int k = 0; k < m; k++) {
                int sidx = __shfl(r.x, k);
                int dl = __shfl(r.y, k);
                float v = xsrc[(size_t)sidx * 64 + lane];
                atomicAdd(&acc[dl * 64 + lane], v);
                if (lane == 0) atomicAdd(&cl[dl], 1.f);
            }
        }
    }
    __syncthreads();
    size_t db = (size_t)b * BS;
    for (int i = tid * 4; i < BS * 64; i += 1024) {
        int d = i >> 6;
        if (db + d < (size_t)n_dst) {
            float4 v = *(float4*)&acc[i];
            ushort4 o;
            o.x = f2bf(v.x); o.y = f2bf(v.y); o.z = f2bf(v.z); o.w = f2bf(v.w);
            *(ushort4*)(agg + db * 64 + i) = o;
        }
    }
    if (tid < BS && db + tid < (size_t)n_dst) cnt[db + tid] = cl[tid];
}

// Layer-2 scalar aggregation: sum2[dst] += s_pat[src].
__global__ __launch_bounds__(256) void scatter_scalar_kernel(
    const float* __restrict__ sval, const int* __restrict__ src,
    const int* __restrict__ dst, float* __restrict__ sum2, int E)
{
    int e = blockIdx.x * 256 + threadIdx.x;
    if (e < E) atomicAdd(&sum2[dst[e]], sval[src[e]]);
}

__device__ inline bfrag8 ld_cvt8(const float* p) {
    f32x4 v0 = *(const f32x4*)p;
    f32x4 v1 = *(const f32x4*)(p + 4);
    bfrag8 r;
    r[0] = (short)f2bf(v0[0]); r[1] = (short)f2bf(v0[1]);
    r[2] = (short)f2bf(v0[2]); r[3] = (short)f2bf(v0[3]);
    r[4] = (short)f2bf(v1[0]); r[5] = (short)f2bf(v1[1]);
    r[6] = (short)f2bf(v1[2]); r[7] = (short)f2bf(v1[3]);
    return r;
}

// MFMA node transform (unchanged from R3). One wave = 16 nodes.
__global__ __launch_bounds__(256) void transform_mfma_kernel(
    const ushort_t* __restrict__ agg, const float* __restrict__ cnt,
    const float* __restrict__ x_in,
    const ushort_t* __restrict__ fragWl, const ushort_t* __restrict__ fragWr,
    const float* __restrict__ bias, const float* __restrict__ cvec,
    const float* __restrict__ sum2, const float* __restrict__ c0p,
    float* __restrict__ out, int nwaves, int add_extra)
{
    int wid = blockIdx.x * 4 + (threadIdx.x >> 6);
    if (wid >= nwaves) return;
    int l = threadIdx.x & 63;
    int m = l & 15;
    int q = l >> 4;
    int nb = wid * 16;
    int row = nb + m;

    const ushort_t* ar = agg + (size_t)row * D;
    bfrag8 a0 = *(const bfrag8*)(ar + q * 8);
    bfrag8 a1 = *(const bfrag8*)(ar + 32 + q * 8);
    const float* xp = x_in + (size_t)row * D;
    bfrag8 x0 = ld_cvt8(xp + q * 8);
    bfrag8 x1 = ld_cvt8(xp + 32 + q * 8);

    f32x4 c4 = *(const f32x4*)(cnt + nb + q * 4);
    f32x4 invc4;
#pragma unroll
    for (int r = 0; r < 4; r++) invc4[r] = 1.0f / fmaxf(c4[r], 1.0f);

    float bias_v[8], cvec_v[8];
#pragma unroll
    for (int jt = 0; jt < 8; jt++) {
        bias_v[jt] = bias[jt * 16 + m];
        cvec_v[jt] = cvec[jt * 16 + m];
    }

    f32x4 p = {0.f, 0.f, 0.f, 0.f};
#pragma unroll
    for (int jt = 0; jt < 8; jt++) {
        const bfrag8* bl0 = (const bfrag8*)(fragWl + ((size_t)(jt * 2 + 0) * 64 + l) * 8);
        const bfrag8* bl1 = (const bfrag8*)(fragWl + ((size_t)(jt * 2 + 1) * 64 + l) * 8);
        const bfrag8* br0 = (const bfrag8*)(fragWr + ((size_t)(jt * 2 + 0) * 64 + l) * 8);
        const bfrag8* br1 = (const bfrag8*)(fragWr + ((size_t)(jt * 2 + 1) * 64 + l) * 8);
        f32x4 accl = {0.f, 0.f, 0.f, 0.f};
        f32x4 accr = {0.f, 0.f, 0.f, 0.f};
        accl = __builtin_amdgcn_mfma_f32_16x16x32_bf16(a0, *bl0, accl, 0, 0, 0);
        accl = __builtin_amdgcn_mfma_f32_16x16x32_bf16(a1, *bl1, accl, 0, 0, 0);
        accr = __builtin_amdgcn_mfma_f32_16x16x32_bf16(x0, *br0, accr, 0, 0, 0);
        accr = __builtin_amdgcn_mfma_f32_16x16x32_bf16(x1, *br1, accr, 0, 0, 0);
        float bj = bias_v[jt], cj = cvec_v[jt];
#pragma unroll
        for (int r = 0; r < 4; r++) {
            float z = accl[r] * invc4[r] + accr[r] + bj;
            p[r] += fmaxf(z, 0.f) * cj;
        }
    }
#pragma unroll
    for (int off = 1; off < 16; off <<= 1) {
        p[0] += __shfl_xor(p[0], off, 16);
        p[1] += __shfl_xor(p[1], off, 16);
        p[2] += __shfl_xor(p[2], off, 16);
        p[3] += __shfl_xor(p[3], off, 16);
    }
    if (m == 0) {
        int base = nb + q * 4;
        f32x4 o = p;
        if (add_extra) {
            float c0 = c0p[0];
#pragma unroll
            for (int r = 0; r < 4; r++)
                o[r] += sum2[base + r] * invc4[r] + c0;
        }
        *(f32x4*)(out + base) = o;
    }
}

extern "C" void kernel_launch(void* const* d_in, const int* in_sizes, int n_in,
                              void* d_out, int out_size, void* d_ws, size_t ws_size,
                              hipStream_t stream)
{
    const float* x_enc  = (const float*)d_in[0];
    const float* x_pat  = (const float*)d_in[1];
    const int*   src_pe = (const int*)d_in[2];
    const int*   dst_pe = (const int*)d_in[3];
    const int*   src_ep = (const int*)d_in[4];
    const int*   dst_ep = (const int*)d_in[5];
    const float* Wl_pe1 = (const float*)d_in[6];
    const float* Wr_pe1 = (const float*)d_in[7];
    const float* b_pe1  = (const float*)d_in[8];
    const float* Wl_ep1 = (const float*)d_in[9];
    const float* Wr_ep1 = (const float*)d_in[10];
    const float* b_ep1  = (const float*)d_in[11];
    const float* Wl_pe2 = (const float*)d_in[12];
    const float* Wr_pe2 = (const float*)d_in[13];
    const float* b_pe2  = (const float*)d_in[14];
    const float* Wc = (const float*)d_in[18];
    const float* bc = (const float*)d_in[19];

    float* ws  = (float*)d_ws;
    float* out = (float*)d_out;

    // zero: sum2 + histograms (~2 MB)
    hipMemsetAsync(d_ws, 0, (size_t)ZERO_FLOATS * sizeof(float), stream);

    prep_kernel<<<128, 256, 0, stream>>>(Wl_pe1, Wr_pe1, Wl_ep1, Wr_ep1,
                                         Wl_pe2, Wr_pe2, b_pe2, Wc, bc, ws);

    int* hist_pe = (int*)(ws + OFF_HIST_PE);
    int* hist_ep = (int*)(ws + OFF_HIST_EP);
    int* base_pe = (int*)(ws + OFF_BASE_PE);
    int* cur_pe  = (int*)(ws + OFF_CUR_PE);
    int* base_ep = (int*)(ws + OFF_BASE_EP);
    int* cur_ep  = (int*)(ws + OFF_CUR_EP);
    int2* recs_pe = (int2*)(ws + OFF_RECS_PE);
    int2* recs_ep = (int2*)(ws + OFF_RECS_EP);
    ushort_t* agg_enc = (ushort_t*)(ws + OFF_AGG_ENC);
    ushort_t* agg_pat = (ushort_t*)(ws + OFF_AGG_PAT);

    // bucket both edge types
    hist_kernel<<<512, 256, 0, stream>>>(dst_pe, NE, hist_pe, SH_PE);
    hist_kernel<<<512, 256, 0, stream>>>(dst_ep, NE, hist_ep, SH_EP);
    scan_kernel<<<1, 1024, 0, stream>>>(hist_pe, base_pe, cur_pe);
    scan_kernel<<<1, 1024, 0, stream>>>(hist_ep, base_ep, cur_ep);
    place_kernel<<<(NE + 255) / 256, 256, 0, stream>>>(
        src_pe, dst_pe, NE, cur_pe, recs_pe, SH_PE, BS_PE - 1);
    place_kernel<<<(NE + 255) / 256, 256, 0, stream>>>(
        src_ep, dst_ep, NE, cur_ep, recs_ep, SH_EP, BS_EP - 1);

    // aggregate per bucket (LDS f32, single bf16 write-out)
    agg_kernel<BS_PE><<<NB_PE, 256, 0, stream>>>(
        x_pat, recs_pe, base_pe, agg_enc, ws + OFF_CNT_ENC, N_ENC);
    agg_kernel<BS_EP><<<NB_EP, 256, 0, stream>>>(
        x_enc, recs_ep, base_ep, agg_pat, ws + OFF_CNT_PAT, N_PAT);

    const ushort_t* frags = (const ushort_t*)(ws + OFF_FRAGS);

    // patient transform -> s_pat; Wl_ep1/Wr_ep1, cvec=wl2c
    int pat_waves = N_PAT / 16;   // 6250
    transform_mfma_kernel<<<(pat_waves + 3) / 4, 256, 0, stream>>>(
        agg_pat, ws + OFF_CNT_PAT, x_pat,
        frags + 2 * 8192, frags + 3 * 8192, b_ep1, ws + OFF_WL2C,
        nullptr, nullptr, ws + OFF_SPAT, pat_waves, 0);

    // layer-2 scalar aggregation
    scatter_scalar_kernel<<<(NE + 255) / 256, 256, 0, stream>>>(
        ws + OFF_SPAT, src_pe, dst_pe, ws + OFF_SUM2, NE);

    // encounter transform -> logits; Wl_pe1/Wr_pe1, cvec=wr2c
    int enc_waves = N_ENC / 16;   // 31250
    transform_mfma_kernel<<<(enc_waves + 3) / 4, 256, 0, stream>>>(
        agg_enc, ws + OFF_CNT_ENC, x_enc,
        frags + 0 * 8192, frags + 1 * 8192, b_pe1, ws + OFF_WR2C,
        ws + OFF_SUM2, ws + OFF_C0, out, enc_waves, 1);
}

// Round 5
// 711.015 us; speedup vs baseline: 2.2854x; 2.2854x over previous
//
#include <hip/hip_runtime.h>
#include <hip/hip_bf16.h>

// Problem constants (from reference)
#define N_ENC 500000
#define N_PAT 100000
#define D 64
#define HID 128
#define NE 1000000

typedef unsigned short ushort_t;
typedef unsigned int uint_t;
typedef __attribute__((ext_vector_type(8))) short bfrag8;   // 8 x bf16 (4 VGPRs)
typedef __attribute__((ext_vector_type(4))) float f32x4;

// Workspace layout (float units). Zeroed region first (one small memset).
#define OFF_HIST_ENC 0              // 500,000 ints
#define OFF_HIST_PAT 500000         // 100,000 ints
#define ZERO_FLOATS  600000         // 2.4 MB zeroed
#define OFF_EXCL_ENC 600000         // 500,000
#define OFF_EXCL_PAT 1100000        // 100,000
#define OFF_PART_ENC 1200000        // 1024
#define OFF_PART_PAT 1201024        // 1024
#define OFF_BASE_ENC 1202048        // 500,001 (padded to 500,032)
#define OFF_CUR_ENC  1702080        // 500,000
#define OFF_BASE_PAT 2202080        // 100,001 (padded to 100,032)
#define OFF_CUR_PAT  2302112        // 100,000
#define OFF_CSR_PE   2402112        // 1,000,000 ints (src per edge, dst-sorted)
#define OFF_CSR_EP   3402112        // 1,000,000 ints
#define OFF_AGG_ENC  4402112        // 500,000*64 bf16 = 16,000,000 floats
#define OFF_AGG_PAT  20402112       // 100,000*64 bf16 = 3,200,000 floats
#define OFF_CNT_ENC  23602112       // 500,000
#define OFF_CNT_PAT  24102112       // 100,000
#define OFF_SUM2     24202112       // 500,000
#define OFF_SPAT     24702112       // 100,000
#define OFF_FRAGS    24802112       // 4 matrices * 8192 ushort = 16,384 floats
#define OFF_WL2C     24818496       // 128
#define OFF_WR2C     24818624       // 128
#define OFF_C0       24818752       // 64
// end ~24.82M floats ~99.3 MB

__device__ inline ushort_t f2bf(float x) {
    // round-to-nearest-even f32 -> bf16
    uint_t u = __float_as_uint(x);
    u += 0x7fffu + ((u >> 16) & 1u);
    return (ushort_t)(u >> 16);
}

// ---------------- Prep (weights -> MFMA fragments; layer-2 collapse) --------
__global__ __launch_bounds__(256) void prep_kernel(
    const float* __restrict__ Wl_pe1, const float* __restrict__ Wr_pe1,
    const float* __restrict__ Wl_ep1, const float* __restrict__ Wr_ep1,
    const float* __restrict__ Wl_pe2, const float* __restrict__ Wr_pe2,
    const float* __restrict__ b_pe2, const float* __restrict__ Wc,
    const float* __restrict__ bc, float* __restrict__ ws)
{
    int t = blockIdx.x * blockDim.x + threadIdx.x;
    const int total = 4 * 8192;
    ushort_t* fr = (ushort_t*)(ws + OFF_FRAGS);
    for (int i = t; i < total; i += gridDim.x * blockDim.x) {
        int mtx = i >> 13;
        int r = i & 8191;
        int jj = r & 7;
        int l = (r >> 3) & 63;
        int ft = r >> 9;          // 0..15 = jt*2+kt
        int kt = ft & 1;
        int jt = ft >> 1;
        int k = kt * 32 + (l >> 4) * 8 + jj;
        int j = jt * 16 + (l & 15);
        const float* W = (mtx == 0) ? Wl_pe1 : (mtx == 1) ? Wr_pe1
                       : (mtx == 2) ? Wl_ep1 : Wr_ep1;
        fr[i] = f2bf(W[k * HID + j]);
    }
    if (blockIdx.x == 0) {
        int tid = threadIdx.x;
        if (tid < HID) {
            float s1 = 0.f, s2 = 0.f;
            for (int j = 0; j < HID; j++) {
                float wc = Wc[j];
                s1 += Wl_pe2[tid * HID + j] * wc;
                s2 += Wr_pe2[tid * HID + j] * wc;
            }
            ws[OFF_WL2C + tid] = s1;
            ws[OFF_WR2C + tid] = s2;
            if (tid == 0) {
                float c0 = bc[0];
                for (int j = 0; j < HID; j++) c0 += b_pe2[j] * Wc[j];
                ws[OFF_C0] = c0;
            }
        }
    }
}

// ---------------- CSR build: hist -> scan -> place --------------------------

__global__ __launch_bounds__(256) void hist_kernel(
    const int* __restrict__ dst, int E, int* __restrict__ hist)
{
    int e = blockIdx.x * 256 + threadIdx.x;
    if (e < E) atomicAdd(&hist[dst[e]], 1);
}

// Per-1024-block exclusive scan; block sums to partials.
__global__ __launch_bounds__(1024) void scan_block_kernel(
    const int* __restrict__ in, int n, int* __restrict__ excl,
    int* __restrict__ partials)
{
    __shared__ int buf[1024];
    int t = threadIdx.x;
    int g = blockIdx.x * 1024 + t;
    int v = (g < n) ? in[g] : 0;
    buf[t] = v;
    __syncthreads();
    for (int off = 1; off < 1024; off <<= 1) {
        int u = (t >= off) ? buf[t - off] : 0;
        __syncthreads();
        buf[t] += u;
        __syncthreads();
    }
    if (g < n) excl[g] = buf[t] - v;
    if (t == 1023) partials[blockIdx.x] = buf[t];
}

// Exclusive scan of partials in place (np <= 1024). Single block.
__global__ __launch_bounds__(1024) void scan_partials_kernel(
    int* __restrict__ partials, int np)
{
    __shared__ int buf[1024];
    int t = threadIdx.x;
    int v = (t < np) ? partials[t] : 0;
    buf[t] = v;
    __syncthreads();
    for (int off = 1; off < 1024; off <<= 1) {
        int u = (t >= off) ? buf[t - off] : 0;
        __syncthreads();
        buf[t] += u;
        __syncthreads();
    }
    if (t < np) partials[t] = buf[t] - v;
}

// base[g] = excl[g] + partials[g>>10]  (g<n); base[n] = total; cur = base.
__global__ __launch_bounds__(256) void scan_final_kernel(
    const int* __restrict__ excl, const int* __restrict__ partials, int n,
    int total, int* __restrict__ base, int* __restrict__ cur)
{
    int g = blockIdx.x * 256 + threadIdx.x;
    if (g < n) {
        int v = excl[g] + partials[g >> 10];
        base[g] = v;
        cur[g] = v;
    } else if (g == n) {
        base[g] = total;
    }
}

// Scatter src-ids into dst-sorted CSR order.
__global__ __launch_bounds__(256) void place_kernel(
    const int* __restrict__ src, const int* __restrict__ dst, int E,
    int* __restrict__ cur, int* __restrict__ csr)
{
    int e = blockIdx.x * 256 + threadIdx.x;
    if (e < E) {
        int pos = atomicAdd(&cur[dst[e]], 1);
        csr[pos] = src[e];
    }
}

// ---------------- CSR gather aggregation (zero atomics) ---------------------
// 32 threads per destination node; thread owns features [2p, 2p+1].
// f32 accumulate over the node's edge list, single bf16x2 store.
// Optionally also computes sum2[d] = sum_e sval[src_e] (layer-2, fused).
__global__ __launch_bounds__(256) void gather_agg_kernel(
    const float* __restrict__ xsrc, const int* __restrict__ csr,
    const int* __restrict__ base, ushort_t* __restrict__ agg,
    float* __restrict__ cnt, const float* __restrict__ sval,
    float* __restrict__ sum2, int n_dst)
{
    int t = blockIdx.x * 256 + threadIdx.x;
    int d = t >> 5;
    if (d >= n_dst) return;
    int p = t & 31;
    int s0 = base[d], s1 = base[d + 1];
    float ax = 0.f, ay = 0.f, sa = 0.f;
    for (int e = s0; e < s1; e++) {
        int s = csr[e];                      // uniform across the 32-lane group
        float2 v = *(const float2*)(xsrc + (size_t)s * D + p * 2);
        ax += v.x;
        ay += v.y;
        if (sval) sa += sval[s];             // uniform broadcast load
    }
    uint_t packed = (uint_t)f2bf(ax) | ((uint_t)f2bf(ay) << 16);
    *(uint_t*)(agg + (size_t)d * D + p * 2) = packed;
    if (p == 0) {
        cnt[d] = (float)(s1 - s0);
        if (sum2) sum2[d] = sa;
    }
}

// ---------------- MFMA node transform (unchanged) ---------------------------
__device__ inline bfrag8 ld_cvt8(const float* p) {
    f32x4 v0 = *(const f32x4*)p;
    f32x4 v1 = *(const f32x4*)(p + 4);
    bfrag8 r;
    r[0] = (short)f2bf(v0[0]); r[1] = (short)f2bf(v0[1]);
    r[2] = (short)f2bf(v0[2]); r[3] = (short)f2bf(v0[3]);
    r[4] = (short)f2bf(v1[0]); r[5] = (short)f2bf(v1[1]);
    r[6] = (short)f2bf(v1[2]); r[7] = (short)f2bf(v1[3]);
    return r;
}

// One wave = 16 nodes. zL = agg_sum @ Wl; zR = x @ Wr;
// z = zL*invc + zR + bias; out = sum_j relu(z)*cvec[j] (+ sum2/cnt + c0).
// A-frag: lane holds A[m=lane&15][k=(lane>>4)*8+jj]
// B-frag: lane holds B[k=(lane>>4)*8+jj][n=lane&15] (pre-packed)
// C/D: col(j)=lane&15, row(node)=(lane>>4)*4+reg (m89/m91-verified)
__global__ __launch_bounds__(256) void transform_mfma_kernel(
    const ushort_t* __restrict__ agg, const float* __restrict__ cnt,
    const float* __restrict__ x_in,
    const ushort_t* __restrict__ fragWl, const ushort_t* __restrict__ fragWr,
    const float* __restrict__ bias, const float* __restrict__ cvec,
    const float* __restrict__ sum2, const float* __restrict__ c0p,
    float* __restrict__ out, int nwaves, int add_extra)
{
    int wid = blockIdx.x * 4 + (threadIdx.x >> 6);
    if (wid >= nwaves) return;
    int l = threadIdx.x & 63;
    int m = l & 15;
    int q = l >> 4;
    int nb = wid * 16;
    int row = nb + m;

    const ushort_t* ar = agg + (size_t)row * D;
    bfrag8 a0 = *(const bfrag8*)(ar + q * 8);
    bfrag8 a1 = *(const bfrag8*)(ar + 32 + q * 8);
    const float* xp = x_in + (size_t)row * D;
    bfrag8 x0 = ld_cvt8(xp + q * 8);
    bfrag8 x1 = ld_cvt8(xp + 32 + q * 8);

    f32x4 c4 = *(const f32x4*)(cnt + nb + q * 4);
    f32x4 invc4;
#pragma unroll
    for (int r = 0; r < 4; r++) invc4[r] = 1.0f / fmaxf(c4[r], 1.0f);

    float bias_v[8], cvec_v[8];
#pragma unroll
    for (int jt = 0; jt < 8; jt++) {
        bias_v[jt] = bias[jt * 16 + m];
        cvec_v[jt] = cvec[jt * 16 + m];
    }

    f32x4 p = {0.f, 0.f, 0.f, 0.f};
#pragma unroll
    for (int jt = 0; jt < 8; jt++) {
        const bfrag8* bl0 = (const bfrag8*)(fragWl + ((size_t)(jt * 2 + 0) * 64 + l) * 8);
        const bfrag8* bl1 = (const bfrag8*)(fragWl + ((size_t)(jt * 2 + 1) * 64 + l) * 8);
        const bfrag8* br0 = (const bfrag8*)(fragWr + ((size_t)(jt * 2 + 0) * 64 + l) * 8);
        const bfrag8* br1 = (const bfrag8*)(fragWr + ((size_t)(jt * 2 + 1) * 64 + l) * 8);
        f32x4 accl = {0.f, 0.f, 0.f, 0.f};
        f32x4 accr = {0.f, 0.f, 0.f, 0.f};
        accl = __builtin_amdgcn_mfma_f32_16x16x32_bf16(a0, *bl0, accl, 0, 0, 0);
        accl = __builtin_amdgcn_mfma_f32_16x16x32_bf16(a1, *bl1, accl, 0, 0, 0);
        accr = __builtin_amdgcn_mfma_f32_16x16x32_bf16(x0, *br0, accr, 0, 0, 0);
        accr = __builtin_amdgcn_mfma_f32_16x16x32_bf16(x1, *br1, accr, 0, 0, 0);
        float bj = bias_v[jt], cj = cvec_v[jt];
#pragma unroll
        for (int r = 0; r < 4; r++) {
            float z = accl[r] * invc4[r] + accr[r] + bj;
            p[r] += fmaxf(z, 0.f) * cj;
        }
    }
#pragma unroll
    for (int off = 1; off < 16; off <<= 1) {
        p[0] += __shfl_xor(p[0], off, 16);
        p[1] += __shfl_xor(p[1], off, 16);
        p[2] += __shfl_xor(p[2], off, 16);
        p[3] += __shfl_xor(p[3], off, 16);
    }
    if (m == 0) {
        int base = nb + q * 4;
        f32x4 o = p;
        if (add_extra) {
            float c0 = c0p[0];
#pragma unroll
            for (int r = 0; r < 4; r++)
                o[r] += sum2[base + r] * invc4[r] + c0;
        }
        *(f32x4*)(out + base) = o;
    }
}

extern "C" void kernel_launch(void* const* d_in, const int* in_sizes, int n_in,
                              void* d_out, int out_size, void* d_ws, size_t ws_size,
                              hipStream_t stream)
{
    const float* x_enc  = (const float*)d_in[0];
    const float* x_pat  = (const float*)d_in[1];
    const int*   src_pe = (const int*)d_in[2];
    const int*   dst_pe = (const int*)d_in[3];
    const int*   src_ep = (const int*)d_in[4];
    const int*   dst_ep = (const int*)d_in[5];
    const float* Wl_pe1 = (const float*)d_in[6];
    const float* Wr_pe1 = (const float*)d_in[7];
    const float* b_pe1  = (const float*)d_in[8];
    const float* Wl_ep1 = (const float*)d_in[9];
    const float* Wr_ep1 = (const float*)d_in[10];
    const float* b_ep1  = (const float*)d_in[11];
    const float* Wl_pe2 = (const float*)d_in[12];
    const float* Wr_pe2 = (const float*)d_in[13];
    const float* b_pe2  = (const float*)d_in[14];
    const float* Wc = (const float*)d_in[18];
    const float* bc = (const float*)d_in[19];

    float* ws  = (float*)d_ws;
    float* out = (float*)d_out;

    // zero: histograms only (~2.4 MB)
    hipMemsetAsync(d_ws, 0, (size_t)ZERO_FLOATS * sizeof(float), stream);

    prep_kernel<<<128, 256, 0, stream>>>(Wl_pe1, Wr_pe1, Wl_ep1, Wr_ep1,
                                         Wl_pe2, Wr_pe2, b_pe2, Wc, bc, ws);

    int* hist_enc = (int*)(ws + OFF_HIST_ENC);
    int* hist_pat = (int*)(ws + OFF_HIST_PAT);
    int* excl_enc = (int*)(ws + OFF_EXCL_ENC);
    int* excl_pat = (int*)(ws + OFF_EXCL_PAT);
    int* part_enc = (int*)(ws + OFF_PART_ENC);
    int* part_pat = (int*)(ws + OFF_PART_PAT);
    int* base_enc = (int*)(ws + OFF_BASE_ENC);
    int* cur_enc  = (int*)(ws + OFF_CUR_ENC);
    int* base_pat = (int*)(ws + OFF_BASE_PAT);
    int* cur_pat  = (int*)(ws + OFF_CUR_PAT);
    int* csr_pe   = (int*)(ws + OFF_CSR_PE);
    int* csr_ep   = (int*)(ws + OFF_CSR_EP);
    ushort_t* agg_enc = (ushort_t*)(ws + OFF_AGG_ENC);
    ushort_t* agg_pat = (ushort_t*)(ws + OFF_AGG_PAT);

    int eblocks = (NE + 255) / 256;

    // CSR for pe (dst = encounters) and ep (dst = patients)
    hist_kernel<<<eblocks, 256, 0, stream>>>(dst_pe, NE, hist_enc);
    hist_kernel<<<eblocks, 256, 0, stream>>>(dst_ep, NE, hist_pat);

    int nb_enc = (N_ENC + 1023) / 1024;   // 489
    int nb_pat = (N_PAT + 1023) / 1024;   // 98
    scan_block_kernel<<<nb_enc, 1024, 0, stream>>>(hist_enc, N_ENC, excl_enc, part_enc);
    scan_partials_kernel<<<1, 1024, 0, stream>>>(part_enc, nb_enc);
    scan_final_kernel<<<(N_ENC + 256) / 256, 256, 0, stream>>>(
        excl_enc, part_enc, N_ENC, NE, base_enc, cur_enc);
    scan_block_kernel<<<nb_pat, 1024, 0, stream>>>(hist_pat, N_PAT, excl_pat, part_pat);
    scan_partials_kernel<<<1, 1024, 0, stream>>>(part_pat, nb_pat);
    scan_final_kernel<<<(N_PAT + 256) / 256, 256, 0, stream>>>(
        excl_pat, part_pat, N_PAT, NE, base_pat, cur_pat);

    place_kernel<<<eblocks, 256, 0, stream>>>(src_pe, dst_pe, NE, cur_enc, csr_pe);
    place_kernel<<<eblocks, 256, 0, stream>>>(src_ep, dst_ep, NE, cur_pat, csr_ep);

    // ep aggregation: agg_pat = sum of x_enc rows per patient
    gather_agg_kernel<<<(N_PAT * 32 + 255) / 256, 256, 0, stream>>>(
        x_enc, csr_ep, base_pat, agg_pat, ws + OFF_CNT_PAT,
        nullptr, nullptr, N_PAT);

    const ushort_t* frags = (const ushort_t*)(ws + OFF_FRAGS);

    // patient transform -> s_pat; Wl_ep1/Wr_ep1, cvec=wl2c
    int pat_waves = N_PAT / 16;   // 6250
    transform_mfma_kernel<<<(pat_waves + 3) / 4, 256, 0, stream>>>(
        agg_pat, ws + OFF_CNT_PAT, x_pat,
        frags + 2 * 8192, frags + 3 * 8192, b_ep1, ws + OFF_WL2C,
        nullptr, nullptr, ws + OFF_SPAT, pat_waves, 0);

    // pe aggregation: agg_enc = sum of x_pat rows per encounter,
    // fused with layer-2 scalar gather sum2 = sum of s_pat[src]
    gather_agg_kernel<<<(N_ENC * 32 + 255) / 256, 256, 0, stream>>>(
        x_pat, csr_pe, base_enc, agg_enc, ws + OFF_CNT_ENC,
        ws + OFF_SPAT, ws + OFF_SUM2, N_ENC);

    // encounter transform -> logits; Wl_pe1/Wr_pe1, cvec=wr2c
    int enc_waves = N_ENC / 16;   // 31250
    transform_mfma_kernel<<<(enc_waves + 3) / 4, 256, 0, stream>>>(
        agg_enc, ws + OFF_CNT_ENC, x_enc,
        frags + 0 * 8192, frags + 1 * 8192, b_pe1, ws + OFF_WR2C,
        ws + OFF_SUM2, ws + OFF_C0, out, enc_waves, 1);
}

// Round 6
// 628.325 us; speedup vs baseline: 2.5862x; 1.1316x over previous
//
#include <hip/hip_runtime.h>
#include <hip/hip_bf16.h>

// Problem constants (from reference)
#define N_ENC 500000
#define N_PAT 100000
#define D 64
#define HID 128
#define NE 1000000

typedef unsigned short ushort_t;
typedef unsigned int uint_t;
typedef __attribute__((ext_vector_type(8))) short bfrag8;   // 8 x bf16 (4 VGPRs)
typedef __attribute__((ext_vector_type(4))) float f32x4;

// Workspace layout (float units). Zeroed region first (one small memset).
#define OFF_HIST_ENC 0              // 500,000 ints
#define OFF_HIST_PAT 500000         // 100,000 ints
#define ZERO_FLOATS  600000         // 2.4 MB zeroed
#define OFF_EXCL_ENC 600000         // 500,000
#define OFF_EXCL_PAT 1100000        // 100,000
#define OFF_PART_ENC 1200000        // 1024
#define OFF_PART_PAT 1201024        // 1024
#define OFF_BASE_ENC 1202048        // 500,001 (pad 500,032)
#define OFF_CUR_ENC  1702080        // 500,000
#define OFF_BASE_PAT 2202080        // 100,001 (pad 100,032)
#define OFF_CUR_PAT  2302112        // 100,000
#define OFF_CSR_PE   2402112        // 1,000,000 ints (src, dst-sorted)
#define OFF_CSR_EP   3402112        // 1,000,000 ints
#define OFF_XBF_ENC  4402112        // 500,000*64 bf16 = 16,000,000 floats
#define OFF_XBF_PAT  20402112       // 100,000*64 bf16 = 3,200,000 floats
#define OFF_SPAT     23602112       // 100,000
#define OFF_FRAGS    23702112       // 4 matrices * 8192 ushort = 16,384 floats
#define OFF_WL2C     23718496       // 128
#define OFF_WR2C     23718624       // 128
#define OFF_C0       23718752       // 64
// end ~23.72M floats ~94.9 MB

__device__ inline ushort_t f2bf(float x) {
    // round-to-nearest-even f32 -> bf16
    uint_t u = __float_as_uint(x);
    u += 0x7fffu + ((u >> 16) & 1u);
    return (ushort_t)(u >> 16);
}

// ---------------- Prep (weights -> MFMA fragments; layer-2 collapse) --------
__global__ __launch_bounds__(256) void prep_kernel(
    const float* __restrict__ Wl_pe1, const float* __restrict__ Wr_pe1,
    const float* __restrict__ Wl_ep1, const float* __restrict__ Wr_ep1,
    const float* __restrict__ Wl_pe2, const float* __restrict__ Wr_pe2,
    const float* __restrict__ b_pe2, const float* __restrict__ Wc,
    const float* __restrict__ bc, float* __restrict__ ws)
{
    int t = blockIdx.x * blockDim.x + threadIdx.x;
    const int total = 4 * 8192;
    ushort_t* fr = (ushort_t*)(ws + OFF_FRAGS);
    for (int i = t; i < total; i += gridDim.x * blockDim.x) {
        int mtx = i >> 13;
        int r = i & 8191;
        int jj = r & 7;
        int l = (r >> 3) & 63;
        int ft = r >> 9;          // 0..15 = jt*2+kt
        int kt = ft & 1;
        int jt = ft >> 1;
        int k = kt * 32 + (l >> 4) * 8 + jj;
        int j = jt * 16 + (l & 15);
        const float* W = (mtx == 0) ? Wl_pe1 : (mtx == 1) ? Wr_pe1
                       : (mtx == 2) ? Wl_ep1 : Wr_ep1;
        fr[i] = f2bf(W[k * HID + j]);
    }
    if (blockIdx.x == 0) {
        int tid = threadIdx.x;
        if (tid < HID) {
            float s1 = 0.f, s2 = 0.f;
            for (int j = 0; j < HID; j++) {
                float wc = Wc[j];
                s1 += Wl_pe2[tid * HID + j] * wc;
                s2 += Wr_pe2[tid * HID + j] * wc;
            }
            ws[OFF_WL2C + tid] = s1;
            ws[OFF_WR2C + tid] = s2;
            if (tid == 0) {
                float c0 = bc[0];
                for (int j = 0; j < HID; j++) c0 += b_pe2[j] * Wc[j];
                ws[OFF_C0] = c0;
            }
        }
    }
}

// f32 -> bf16 conversion, 8 elems/thread.
__global__ __launch_bounds__(256) void cvt_bf16_kernel(
    const float* __restrict__ in, ushort_t* __restrict__ out, int n8)
{
    int i = blockIdx.x * 256 + threadIdx.x;
    if (i >= n8) return;
    const f32x4* p = (const f32x4*)(in + (size_t)i * 8);
    f32x4 v0 = p[0], v1 = p[1];
    uint4 o;
    o.x = (uint_t)f2bf(v0[0]) | ((uint_t)f2bf(v0[1]) << 16);
    o.y = (uint_t)f2bf(v0[2]) | ((uint_t)f2bf(v0[3]) << 16);
    o.z = (uint_t)f2bf(v1[0]) | ((uint_t)f2bf(v1[1]) << 16);
    o.w = (uint_t)f2bf(v1[2]) | ((uint_t)f2bf(v1[3]) << 16);
    *(uint4*)(out + (size_t)i * 8) = o;
}

// ---------------- CSR build: hist -> scan -> place --------------------------

__global__ __launch_bounds__(256) void hist_kernel(
    const int* __restrict__ dst, int E, int* __restrict__ hist)
{
    int e = blockIdx.x * 256 + threadIdx.x;
    if (e < E) atomicAdd(&hist[dst[e]], 1);
}

__global__ __launch_bounds__(1024) void scan_block_kernel(
    const int* __restrict__ in, int n, int* __restrict__ excl,
    int* __restrict__ partials)
{
    __shared__ int buf[1024];
    int t = threadIdx.x;
    int g = blockIdx.x * 1024 + t;
    int v = (g < n) ? in[g] : 0;
    buf[t] = v;
    __syncthreads();
    for (int off = 1; off < 1024; off <<= 1) {
        int u = (t >= off) ? buf[t - off] : 0;
        __syncthreads();
        buf[t] += u;
        __syncthreads();
    }
    if (g < n) excl[g] = buf[t] - v;
    if (t == 1023) partials[blockIdx.x] = buf[t];
}

__global__ __launch_bounds__(1024) void scan_partials_kernel(
    int* __restrict__ partials, int np)
{
    __shared__ int buf[1024];
    int t = threadIdx.x;
    int v = (t < np) ? partials[t] : 0;
    buf[t] = v;
    __syncthreads();
    for (int off = 1; off < 1024; off <<= 1) {
        int u = (t >= off) ? buf[t - off] : 0;
        __syncthreads();
        buf[t] += u;
        __syncthreads();
    }
    if (t < np) partials[t] = buf[t] - v;
}

__global__ __launch_bounds__(256) void scan_final_kernel(
    const int* __restrict__ excl, const int* __restrict__ partials, int n,
    int total, int* __restrict__ base, int* __restrict__ cur)
{
    int g = blockIdx.x * 256 + threadIdx.x;
    if (g < n) {
        int v = excl[g] + partials[g >> 10];
        base[g] = v;
        cur[g] = v;
    } else if (g == n) {
        base[g] = total;
    }
}

__global__ __launch_bounds__(256) void place_kernel(
    const int* __restrict__ src, const int* __restrict__ dst, int E,
    int* __restrict__ cur, int* __restrict__ csr)
{
    int e = blockIdx.x * 256 + threadIdx.x;
    if (e < E) {
        int pos = atomicAdd(&cur[dst[e]], 1);
        csr[pos] = src[e];
    }
}

// ---------------- Fused gather + MFMA transform -----------------------------
// One wave = 16 nodes. Lane (m=l&15, q=l>>4) gathers its own A-frag slice
// A[m][k=q*8..q*8+7, 32+q*8..+7] from bf16 source rows over the node's CSR
// edge list (f32 accumulate -> bf16 frags). deg and the fused layer-2 scalar
// sum come from base[] / in-loop gather + lane shuffles. No agg/cnt/sum2
// arrays, no separate gather dispatch.
//   zL = sum_edges x_src @ Wl ; zR = x_dst @ Wr
//   z  = zL*invc + zR + bias ; out = sum_j relu(z)*cvec[j] (+ sa*invc + c0)
// A-frag: lane holds A[m=lane&15][k=(lane>>4)*8+jj]
// B-frag: lane holds B[k=(lane>>4)*8+jj][n=lane&15] (pre-packed)
// C/D: col(j)=lane&15, row(node)=(lane>>4)*4+reg (m89/m91-verified)
__global__ __launch_bounds__(256) void transform_fused_kernel(
    const ushort_t* __restrict__ xsrc, const int* __restrict__ csr,
    const int* __restrict__ base, const ushort_t* __restrict__ xdst,
    const ushort_t* __restrict__ fragWl, const ushort_t* __restrict__ fragWr,
    const float* __restrict__ bias, const float* __restrict__ cvec,
    const float* __restrict__ sval, const float* __restrict__ c0p,
    float* __restrict__ out, int nwaves, int add_extra)
{
    int wid = blockIdx.x * 4 + (threadIdx.x >> 6);
    if (wid >= nwaves) return;
    int l = threadIdx.x & 63;
    int m = l & 15;
    int q = l >> 4;
    int nb = wid * 16;
    int row = nb + m;

    int s0 = base[row], s1 = base[row + 1];
    float degf = (float)(s1 - s0);

    // gather-accumulate this lane's 16 A elements (k = q*8.., 32+q*8..)
    float accf[16];
#pragma unroll
    for (int i = 0; i < 16; i++) accf[i] = 0.f;
    float sa = 0.f;
    for (int e = s0; e < s1; e++) {
        int s = csr[e];
        const uint_t* xr = (const uint_t*)(xsrc + (size_t)s * D);
        uint4 w0 = *(const uint4*)(xr + q * 4);
        uint4 w1 = *(const uint4*)(xr + 16 + q * 4);
        uint_t dw[8] = {w0.x, w0.y, w0.z, w0.w, w1.x, w1.y, w1.z, w1.w};
#pragma unroll
        for (int i = 0; i < 8; i++) {
            accf[2 * i]     += __uint_as_float(dw[i] << 16);
            accf[2 * i + 1] += __uint_as_float(dw[i] & 0xffff0000u);
        }
        if (add_extra) sa += sval[s];
    }
    bfrag8 a0, a1;
#pragma unroll
    for (int i = 0; i < 8; i++) {
        a0[i] = (short)f2bf(accf[i]);
        a1[i] = (short)f2bf(accf[8 + i]);
    }

    // dst-feature frags: direct bf16 loads
    const ushort_t* xd = xdst + (size_t)row * D;
    bfrag8 x0 = *(const bfrag8*)(xd + q * 8);
    bfrag8 x1 = *(const bfrag8*)(xd + 32 + q * 8);

    // invc for the 4 C-rows (nodes nb+q*4+r) this lane's accumulator holds
    f32x4 invc4;
#pragma unroll
    for (int r = 0; r < 4; r++) {
        float dg = __shfl(degf, q * 4 + r);   // lanes 0..15 hold node nb+l's deg
        invc4[r] = 1.0f / fmaxf(dg, 1.0f);
    }

    float bias_v[8], cvec_v[8];
#pragma unroll
    for (int jt = 0; jt < 8; jt++) {
        bias_v[jt] = bias[jt * 16 + m];
        cvec_v[jt] = cvec[jt * 16 + m];
    }

    f32x4 p = {0.f, 0.f, 0.f, 0.f};
#pragma unroll
    for (int jt = 0; jt < 8; jt++) {
        const bfrag8* bl0 = (const bfrag8*)(fragWl + ((size_t)(jt * 2 + 0) * 64 + l) * 8);
        const bfrag8* bl1 = (const bfrag8*)(fragWl + ((size_t)(jt * 2 + 1) * 64 + l) * 8);
        const bfrag8* br0 = (const bfrag8*)(fragWr + ((size_t)(jt * 2 + 0) * 64 + l) * 8);
        const bfrag8* br1 = (const bfrag8*)(fragWr + ((size_t)(jt * 2 + 1) * 64 + l) * 8);
        f32x4 accl = {0.f, 0.f, 0.f, 0.f};
        f32x4 accr = {0.f, 0.f, 0.f, 0.f};
        accl = __builtin_amdgcn_mfma_f32_16x16x32_bf16(a0, *bl0, accl, 0, 0, 0);
        accl = __builtin_amdgcn_mfma_f32_16x16x32_bf16(a1, *bl1, accl, 0, 0, 0);
        accr = __builtin_amdgcn_mfma_f32_16x16x32_bf16(x0, *br0, accr, 0, 0, 0);
        accr = __builtin_amdgcn_mfma_f32_16x16x32_bf16(x1, *br1, accr, 0, 0, 0);
        float bj = bias_v[jt], cj = cvec_v[jt];
#pragma unroll
        for (int r = 0; r < 4; r++) {
            float z = accl[r] * invc4[r] + accr[r] + bj;
            p[r] += fmaxf(z, 0.f) * cj;
        }
    }
#pragma unroll
    for (int off = 1; off < 16; off <<= 1) {
        p[0] += __shfl_xor(p[0], off, 16);
        p[1] += __shfl_xor(p[1], off, 16);
        p[2] += __shfl_xor(p[2], off, 16);
        p[3] += __shfl_xor(p[3], off, 16);
    }
    // layer-2 scalar sums for this quad's 4 nodes (from lanes 0..15)
    f32x4 sa4;
#pragma unroll
    for (int r = 0; r < 4; r++) sa4[r] = __shfl(sa, q * 4 + r);
    if (m == 0) {
        int basen = nb + q * 4;
        f32x4 o = p;
        if (add_extra) {
            float c0 = c0p[0];
#pragma unroll
            for (int r = 0; r < 4; r++)
                o[r] += sa4[r] * invc4[r] + c0;
        }
        *(f32x4*)(out + basen) = o;
    }
}

extern "C" void kernel_launch(void* const* d_in, const int* in_sizes, int n_in,
                              void* d_out, int out_size, void* d_ws, size_t ws_size,
                              hipStream_t stream)
{
    const float* x_enc  = (const float*)d_in[0];
    const float* x_pat  = (const float*)d_in[1];
    const int*   src_pe = (const int*)d_in[2];
    const int*   dst_pe = (const int*)d_in[3];
    const int*   src_ep = (const int*)d_in[4];
    const int*   dst_ep = (const int*)d_in[5];
    const float* Wl_pe1 = (const float*)d_in[6];
    const float* Wr_pe1 = (const float*)d_in[7];
    const float* b_pe1  = (const float*)d_in[8];
    const float* Wl_ep1 = (const float*)d_in[9];
    const float* Wr_ep1 = (const float*)d_in[10];
    const float* b_ep1  = (const float*)d_in[11];
    const float* Wl_pe2 = (const float*)d_in[12];
    const float* Wr_pe2 = (const float*)d_in[13];
    const float* b_pe2  = (const float*)d_in[14];
    const float* Wc = (const float*)d_in[18];
    const float* bc = (const float*)d_in[19];

    float* ws  = (float*)d_ws;
    float* out = (float*)d_out;

    // zero: histograms only (~2.4 MB)
    hipMemsetAsync(d_ws, 0, (size_t)ZERO_FLOATS * sizeof(float), stream);

    prep_kernel<<<128, 256, 0, stream>>>(Wl_pe1, Wr_pe1, Wl_ep1, Wr_ep1,
                                         Wl_pe2, Wr_pe2, b_pe2, Wc, bc, ws);

    int* hist_enc = (int*)(ws + OFF_HIST_ENC);
    int* hist_pat = (int*)(ws + OFF_HIST_PAT);
    int* excl_enc = (int*)(ws + OFF_EXCL_ENC);
    int* excl_pat = (int*)(ws + OFF_EXCL_PAT);
    int* part_enc = (int*)(ws + OFF_PART_ENC);
    int* part_pat = (int*)(ws + OFF_PART_PAT);
    int* base_enc = (int*)(ws + OFF_BASE_ENC);
    int* cur_enc  = (int*)(ws + OFF_CUR_ENC);
    int* base_pat = (int*)(ws + OFF_BASE_PAT);
    int* cur_pat  = (int*)(ws + OFF_CUR_PAT);
    int* csr_pe   = (int*)(ws + OFF_CSR_PE);
    int* csr_ep   = (int*)(ws + OFF_CSR_EP);
    ushort_t* xbf_enc = (ushort_t*)(ws + OFF_XBF_ENC);
    ushort_t* xbf_pat = (ushort_t*)(ws + OFF_XBF_PAT);

    // bf16 feature copies
    cvt_bf16_kernel<<<(N_ENC * D / 8 + 255) / 256, 256, 0, stream>>>(
        x_enc, xbf_enc, N_ENC * D / 8);
    cvt_bf16_kernel<<<(N_PAT * D / 8 + 255) / 256, 256, 0, stream>>>(
        x_pat, xbf_pat, N_PAT * D / 8);

    int eblocks = (NE + 255) / 256;

    // CSR for pe (dst = encounters) and ep (dst = patients)
    hist_kernel<<<eblocks, 256, 0, stream>>>(dst_pe, NE, hist_enc);
    hist_kernel<<<eblocks, 256, 0, stream>>>(dst_ep, NE, hist_pat);

    int nb_enc = (N_ENC + 1023) / 1024;   // 489
    int nb_pat = (N_PAT + 1023) / 1024;   // 98
    scan_block_kernel<<<nb_enc, 1024, 0, stream>>>(hist_enc, N_ENC, excl_enc, part_enc);
    scan_partials_kernel<<<1, 1024, 0, stream>>>(part_enc, nb_enc);
    scan_final_kernel<<<(N_ENC + 256) / 256, 256, 0, stream>>>(
        excl_enc, part_enc, N_ENC, NE, base_enc, cur_enc);
    scan_block_kernel<<<nb_pat, 1024, 0, stream>>>(hist_pat, N_PAT, excl_pat, part_pat);
    scan_partials_kernel<<<1, 1024, 0, stream>>>(part_pat, nb_pat);
    scan_final_kernel<<<(N_PAT + 256) / 256, 256, 0, stream>>>(
        excl_pat, part_pat, N_PAT, NE, base_pat, cur_pat);

    place_kernel<<<eblocks, 256, 0, stream>>>(src_pe, dst_pe, NE, cur_enc, csr_pe);
    place_kernel<<<eblocks, 256, 0, stream>>>(src_ep, dst_ep, NE, cur_pat, csr_ep);

    const ushort_t* frags = (const ushort_t*)(ws + OFF_FRAGS);

    // patient transform (fused ep-gather) -> s_pat; Wl_ep1/Wr_ep1, cvec=wl2c
    int pat_waves = N_PAT / 16;   // 6250
    transform_fused_kernel<<<(pat_waves + 3) / 4, 256, 0, stream>>>(
        xbf_enc, csr_ep, base_pat, xbf_pat,
        frags + 2 * 8192, frags + 3 * 8192, b_ep1, ws + OFF_WL2C,
        nullptr, nullptr, ws + OFF_SPAT, pat_waves, 0);

    // encounter transform (fused pe-gather + layer-2 scalar gather) -> logits
    int enc_waves = N_ENC / 16;   // 31250
    transform_fused_kernel<<<(enc_waves + 3) / 4, 256, 0, stream>>>(
        xbf_pat, csr_pe, base_enc, xbf_enc,
        frags + 0 * 8192, frags + 1 * 8192, b_pe1, ws + OFF_WR2C,
        ws + OFF_SPAT, ws + OFF_C0, out, enc_waves, 1);
}